// Round 14
// baseline (201.856 us; speedup 1.0000x reference)
//
#include <hip/hip_runtime.h>
#include <hip/hip_bf16.h>

// CrossMultiHeadAttention: B=4, N=M=2048, D=1024, H=16, hd=64, f32 in/out.
// bf16 pipeline: cvt(weights only) -> fused QKV GEMM (A staged f32 in-reg cvt,
// double-buffered staging, XOR-swizzled tiles, XCD-colocated panels)
// -> flash attn -> out GEMM (double-buffered too).

typedef __attribute__((ext_vector_type(8))) short bf16x8;
typedef __attribute__((ext_vector_type(4))) float f32x4;
typedef __attribute__((ext_vector_type(16))) float f32x16;
typedef __attribute__((ext_vector_type(4))) unsigned short u16x4;
typedef __attribute__((ext_vector_type(4))) unsigned int u32x4;

#define SEQ 2048
#define H_ 16

static __device__ __forceinline__ unsigned short f2bf(float f) {
  unsigned int u = __float_as_uint(f);
  u += 0x7fffu + ((u >> 16) & 1u);
  return (unsigned short)(u >> 16);
}

static __device__ __forceinline__ void gload16(const void* g, void* l) {
  __builtin_amdgcn_global_load_lds((const __attribute__((address_space(1))) void*)g,
                                   (__attribute__((address_space(3))) void*)l, 16, 0, 0);
}

// Convert the four weight matrices to bf16 (X/E are consumed as f32 by the GEMM).
__global__ __launch_bounds__(256) void k_cvt_w(const float* __restrict__ wq, const float* __restrict__ wk,
    const float* __restrict__ wv, const float* __restrict__ wo,
    unsigned short* __restrict__ Wqb, unsigned short* __restrict__ Wkb,
    unsigned short* __restrict__ Wvb, unsigned short* __restrict__ Wob) {
  int i = blockIdx.x * 256 + threadIdx.x;   // 4 x 262144 float4 groups
  const float* src; unsigned short* dst; int off;
  if (i < 262144)       { src = wq; dst = Wqb; off = i; }
  else if (i < 524288)  { src = wk; dst = Wkb; off = i - 262144; }
  else if (i < 786432)  { src = wv; dst = Wvb; off = i - 524288; }
  else                  { src = wo; dst = Wob; off = i - 786432; }
  float4 v = reinterpret_cast<const float4*>(src)[off];
  u16x4 o;
  o[0] = f2bf(v.x); o[1] = f2bf(v.y); o[2] = f2bf(v.z); o[3] = f2bf(v.w);
  *reinterpret_cast<u16x4*>(dst + (size_t)off * 4) = o;
}

// Shared GEMM core: acc = A_tile[128,1024] @ W_tile[128,1024]^T for one block.
// DOUBLE-BUFFERED staging (prefetch K-step t+1 while computing t).
// Per-buffer smem layout: [A tile (16KB f32-swz or 8KB bf16-swz)][W tile 8KB].
// bf16 tiles use slot^(row&3) XOR swizzle (16B slots within the 64B row) to
// break the 8-way bank conflict of the 64B-row-stride fragment read; the f32
// A tile uses the (row&7)<<4 swizzle within its 128B row. Both are applied on
// the global SOURCE address (linear LDS dest, per global_load_lds rules) and
// re-applied at the read.
template<int F32A, typename EPI>
static __device__ __forceinline__ void gemm_core(char* __restrict__ smem,
                                                 const void* __restrict__ Av,
                                                 const unsigned short* __restrict__ W,
                                                 int col0, int row0, EPI epi) {
  constexpr int ASZ = F32A ? 16384 : 8192;
  constexpr int BUF = ASZ + 8192;
  const int tid = threadIdx.x, lane = tid & 63, w = tid >> 6;
  const int wr = w >> 1, wc = w & 1;
  f32x4 acc[4][4];
  for (int i = 0; i < 4; ++i)
    for (int j = 0; j < 4; ++j)
      for (int e = 0; e < 4; ++e) acc[i][j][e] = 0.f;

  // A staging offsets (source pre-swizzled)
  size_t aoff[F32A ? 4 : 2];
  int aldso[F32A ? 4 : 2];
  if (F32A) {
#pragma unroll
    for (int h = 0; h < 4; ++h) {
      int ch = tid + h * 256;                 // 1024 chunks of 16B (4 f32)
      int row = ch >> 3, colb = (ch & 7) << 4;
      int ge = (colb ^ ((row & 7) << 4)) >> 2;
      aoff[h] = (size_t)(row0 + row) * 1024 + ge;
      aldso[h] = ch * 16;
    }
  } else {
#pragma unroll
    for (int h = 0; h < 2; ++h) {
      int ch = tid + h * 256;                 // 512 chunks of 16B (8 bf16)
      int row = ch >> 2, s = ch & 3;
      aoff[h] = (size_t)(row0 + row) * 1024 + (size_t)((s ^ (row & 3)) * 8);
      aldso[h] = ch * 16;
    }
  }
  // W staging offsets (bf16, source pre-swizzled slot^(row&3))
  size_t woff[2];
  int wldso[2];
#pragma unroll
  for (int h = 0; h < 2; ++h) {
    int ch = tid + h * 256;
    int row = ch >> 2, s = ch & 3;
    woff[h] = (size_t)(col0 + row) * 1024 + (size_t)((s ^ (row & 3)) * 8);
    wldso[h] = ch * 16;
  }

#define GSTAGE(K0, BUFO)                                                      \
  {                                                                           \
    if (F32A) {                                                               \
      const float* Af_ = (const float*)Av;                                    \
      _Pragma("unroll")                                                       \
      for (int h = 0; h < 4; ++h)                                             \
        gload16(Af_ + aoff[h] + (K0), smem + (BUFO) + aldso[h]);              \
    } else {                                                                  \
      const unsigned short* Ab_ = (const unsigned short*)Av;                  \
      _Pragma("unroll")                                                       \
      for (int h = 0; h < 2; ++h)                                             \
        gload16(Ab_ + aoff[h] + (K0), smem + (BUFO) + aldso[h]);              \
    }                                                                         \
    _Pragma("unroll")                                                         \
    for (int h = 0; h < 2; ++h)                                               \
      gload16(W + woff[h] + (K0), smem + (BUFO) + ASZ + wldso[h]);            \
  }

  const int fr = lane & 15, ko = (lane >> 4) * 8;
  const int slot = lane >> 4;   // 16B slot index of this lane's fragment

  GSTAGE(0, 0);

  for (int kt = 0; kt < 32; ++kt) {
    __syncthreads();   // drains vmcnt -> buf[kt&1] ready, other buf free
    const int bo = (kt & 1) * BUF;
    const char* AsB = smem + bo;
    const char* WsB = smem + bo + ASZ;
    if (kt + 1 < 32) GSTAGE((kt + 1) * 32, ((kt + 1) & 1) * BUF);

    bf16x8 af[4], bfr[4];
#pragma unroll
    for (int mi = 0; mi < 4; ++mi) {
      int r = wr * 64 + mi * 16 + fr;
      if (F32A) {
        int swz = (r & 7) << 4;
        int b0 = r * 128 + ko * 4;
        f32x4 x0 = *(const f32x4*)(AsB + ((b0) ^ swz));
        f32x4 x1 = *(const f32x4*)(AsB + ((b0 + 16) ^ swz));
        unsigned pw[4];
        asm("v_cvt_pk_bf16_f32 %0, %1, %2" : "=v"(pw[0]) : "v"(x0[0]), "v"(x0[1]));
        asm("v_cvt_pk_bf16_f32 %0, %1, %2" : "=v"(pw[1]) : "v"(x0[2]), "v"(x0[3]));
        asm("v_cvt_pk_bf16_f32 %0, %1, %2" : "=v"(pw[2]) : "v"(x1[0]), "v"(x1[1]));
        asm("v_cvt_pk_bf16_f32 %0, %1, %2" : "=v"(pw[3]) : "v"(x1[2]), "v"(x1[3]));
        u32x4 fa = { pw[0], pw[1], pw[2], pw[3] };
        af[mi] = __builtin_bit_cast(bf16x8, fa);
      } else {
        af[mi] = *(const bf16x8*)(AsB + r * 64 + ((slot ^ (r & 3)) * 16));
      }
    }
#pragma unroll
    for (int ni = 0; ni < 4; ++ni) {
      int r = wc * 64 + ni * 16 + fr;
      bfr[ni] = *(const bf16x8*)(WsB + r * 64 + ((slot ^ (r & 3)) * 16));
    }
#pragma unroll
    for (int mi = 0; mi < 4; ++mi)
#pragma unroll
      for (int ni = 0; ni < 4; ++ni)
        acc[mi][ni] = __builtin_amdgcn_mfma_f32_16x16x32_bf16(af[mi], bfr[ni], acc[mi][ni], 0, 0, 0);
  }
#undef GSTAGE

  for (int mi = 0; mi < 4; ++mi)
    for (int ni = 0; ni < 4; ++ni) {
      int r0 = row0 + wr * 64 + mi * 16 + (lane >> 4) * 4;
      int o = col0 + wc * 64 + ni * 16 + (lane & 15);
      epi(r0, o, acc[mi][ni]);
    }
}

// XCD co-location decode: all 8 column-blocks of one A row-panel land on the
// same XCD (linear&7 invariant in ec), so the 512KB f32 panel is L2-resident.
static __device__ __forceinline__ void panel_decode(int& col0, int& row0) {
  int lin = blockIdx.x + 8 * blockIdx.y;       // 0..511
  int er = (lin & 7) * 8 + ((lin >> 3) & 7);   // row panel 0..63
  int ec = lin >> 6;                           // col block 0..7
  col0 = ec * 128;
  row0 = er * 128;
}

// Fused Q/K/V projection GEMM; blockIdx.z selects path (block-uniform).
// z=0: Q = X@Wq^T scaled 0.125*log2(e), head layout [B,H,seq,64] bf16.
// z=1: K = E@Wk^T, head layout.
// z=2: V = E@Wv^T, transposed head layout [B,H,64,seq].
__global__ __launch_bounds__(256) void k_gemm_qkv(const float* __restrict__ x,
                                                  const float* __restrict__ e,
                                                  const unsigned short* __restrict__ Wqb,
                                                  const unsigned short* __restrict__ Wkb,
                                                  const unsigned short* __restrict__ Wvb,
                                                  unsigned short* __restrict__ Qb,
                                                  unsigned short* __restrict__ Kb,
                                                  unsigned short* __restrict__ Vtg) {
  __shared__ __align__(16) char smem[2 * (16384 + 8192)];
  const int z = blockIdx.z;
  int col0, row0;
  panel_decode(col0, row0);
  const void* A = (z == 0) ? (const void*)x : (const void*)e;
  const unsigned short* W = (z == 0) ? Wqb : (z == 1) ? Wkb : Wvb;
  if (z == 2) {
    gemm_core<1>(smem, A, W, col0, row0, [&](int r0, int o, f32x4 v) {
      int b = r0 >> 11, n0 = r0 & (SEQ - 1);
      int h = o >> 6, c = o & 63;
      u16x4 o4;
      for (int j = 0; j < 4; ++j) o4[j] = f2bf(v[j]);
      *(u16x4*)&Vtg[(((size_t)(b * H_ + h)) * 64 + c) * SEQ + n0] = o4;
    });
  } else {
    unsigned short* out = (z == 0) ? Qb : Kb;
    const float sc = (z == 0) ? 0.18033688f : 1.0f;   // 0.125 * log2(e)
    gemm_core<1>(smem, A, W, col0, row0, [&](int r0, int o, f32x4 v) {
      int b = r0 >> 11, n0 = r0 & (SEQ - 1);
      int h = o >> 6, c = o & 63;
      for (int j = 0; j < 4; ++j)
        out[(((size_t)(b * H_ + h)) * SEQ + n0 + j) * 64 + c] = f2bf(v[j] * sc);
    });
  }
}

// Final GEMM: out = CTX @ Wo^T, f32 [8192,1024].
__global__ __launch_bounds__(256) void k_gemm_out(const unsigned short* __restrict__ A,
                                                  const unsigned short* __restrict__ W,
                                                  float* __restrict__ out) {
  __shared__ __align__(16) char smem[2 * (8192 + 8192)];
  int col0, row0;
  panel_decode(col0, row0);
  gemm_core<0>(smem, A, W, col0, row0, [&](int r0, int o, f32x4 v) {
    for (int j = 0; j < 4; ++j)
      out[(size_t)(r0 + j) * 1024 + o] = v[j];
  });
}

static __device__ __forceinline__ int swzaddr(int row, int colb) {
  return row * 128 + (colb ^ ((row & 7) << 4));
}

// Flash attention, no-max softmax (Q pre-scaled to exp2 domain; raw v_exp_f32
// is exact for our bounded scores). Q,K in [B,H,seq,64]; Vt in [B,H,64,seq];
// CTX [B*N,1024] bf16. 8 waves x 32 q-rows = 256 q-rows/block (512 thr);
// KV tiles of 64, double-buffered. XCD-affine (bh,qt) decode keeps K/V in each
// XCD's L2 (FETCH 139->41 MB). l via ones-MFMA (no VALU row-sum/merge).
__global__ __launch_bounds__(512) void k_attn(const unsigned short* __restrict__ Qh,
                                              const unsigned short* __restrict__ Kh,
                                              const unsigned short* __restrict__ Vtg,
                                              unsigned short* __restrict__ CTX) {
  __shared__ __align__(16) char lds[4 * 8192];
  const int tid = threadIdx.x, lane = tid & 63, w = tid >> 6;
  const int hi = lane >> 5, q = lane & 31;
  const int id = blockIdx.x;
  const int bh = (id & 7) * 8 + ((id >> 3) & 7);   // XCD-affine head grouping
  const int qt = id >> 6;                          // 0..7 (256 q-rows per block)
  const size_t kvbase = (size_t)bh * (SEQ * 64);
  const size_t qrow = (size_t)bh * SEQ + qt * 256 + w * 32 + q;
  bf16x8 qf[4];
#pragma unroll
  for (int c = 0; c < 4; ++c)
    qf[c] = *(const bf16x8*)&Qh[qrow * 64 + c * 16 + hi * 8];
  f32x16 oacc0, oacc1, oaccL, fzero;
#pragma unroll
  for (int r = 0; r < 16; ++r) { oacc0[r] = 0.f; oacc1[r] = 0.f; oaccL[r] = 0.f; fzero[r] = 0.f; }
  bf16x8 ones;
#pragma unroll
  for (int r = 0; r < 8; ++r) ones[r] = (short)0x3F80;   // bf16 1.0

  // staging: 512 16B chunks per 8KB tile; each of 512 threads stages 1 K-chunk
  // and 1 V-chunk. LDS linear; global source pre-swizzled so reads use
  // colb ^ ((row&7)<<4).
  const int sc = tid;
  const int srow = sc >> 3, spb = (sc & 7) << 4;
  const int sge = (spb ^ ((srow & 7) << 4)) >> 1;
  const size_t koff = (size_t)srow * 64 + sge;   // + t*4096
  const size_t voff = (size_t)srow * SEQ + sge;  // + t*64
  const int ldso = sc * 16;

#define STAGE(T, BUFO)                                                        \
  {                                                                           \
    gload16(Kh + kvbase + (size_t)(T) * 4096 + koff, lds + (BUFO) + ldso);    \
    gload16(Vtg + kvbase + (size_t)(T) * 64 + voff, lds + (BUFO) + 8192 + ldso); \
  }

  STAGE(0, 0);

  for (int t = 0; t < 32; ++t) {
    __syncthreads();  // drains vmcnt -> buf[t&1] ready, buf[t&1^1] free
    const int bo = (t & 1) * 16384;
    char* Kb = lds + bo;
    char* Vb = lds + bo + 8192;
    if (t + 1 < 32) STAGE(t + 1, ((t + 1) & 1) * 16384);

    // QK^T (swapped): s[half] = S^T[key][q], already in exp2 domain
    f32x16 s0, s1;
    __builtin_amdgcn_s_setprio(1);
    {
      bf16x8 kf0 = *(const bf16x8*)(Kb + swzaddr(q, 0 * 32 + hi * 16));
      bf16x8 kf1 = *(const bf16x8*)(Kb + swzaddr(32 + q, 0 * 32 + hi * 16));
      s0 = __builtin_amdgcn_mfma_f32_32x32x16_bf16(kf0, qf[0], fzero, 0, 0, 0);
      s1 = __builtin_amdgcn_mfma_f32_32x32x16_bf16(kf1, qf[0], fzero, 0, 0, 0);
    }
#pragma unroll
    for (int c = 1; c < 4; ++c) {
      bf16x8 kf0 = *(const bf16x8*)(Kb + swzaddr(q, c * 32 + hi * 16));
      bf16x8 kf1 = *(const bf16x8*)(Kb + swzaddr(32 + q, c * 32 + hi * 16));
      s0 = __builtin_amdgcn_mfma_f32_32x32x16_bf16(kf0, qf[c], s0, 0, 0, 0);
      s1 = __builtin_amdgcn_mfma_f32_32x32x16_bf16(kf1, qf[c], s1, 0, 0, 0);
    }
    __builtin_amdgcn_s_setprio(0);

    bf16x8 pfrag[4];

#define SOFT_PACK(SREG, FA, FB)                                               \
    {                                                                         \
      float pa[16];                                                           \
      _Pragma("unroll")                                                       \
      for (int r = 0; r < 16; ++r) pa[r] = __builtin_amdgcn_exp2f(SREG[r]);   \
      unsigned pw[8];                                                         \
      _Pragma("unroll")                                                       \
      for (int i = 0; i < 8; ++i)                                             \
        asm("v_cvt_pk_bf16_f32 %0, %1, %2" : "=v"(pw[i])                      \
            : "v"(pa[2 * i]), "v"(pa[2 * i + 1]));                            \
      asm("v_permlane32_swap_b32 %0, %1" : "+v"(pw[0]), "+v"(pw[2]));         \
      asm("v_permlane32_swap_b32 %0, %1" : "+v"(pw[1]), "+v"(pw[3]));         \
      asm("v_permlane32_swap_b32 %0, %1" : "+v"(pw[4]), "+v"(pw[6]));         \
      asm("v_permlane32_swap_b32 %0, %1" : "+v"(pw[5]), "+v"(pw[7]));         \
      u32x4 fa = { pw[0], pw[1], pw[2], pw[3] };                              \
      u32x4 fb = { pw[4], pw[5], pw[6], pw[7] };                              \
      FA = __builtin_bit_cast(bf16x8, fa);                                    \
      FB = __builtin_bit_cast(bf16x8, fb);                                    \
    }

    SOFT_PACK(s0, pfrag[0], pfrag[1])
    SOFT_PACK(s1, pfrag[2], pfrag[3])
#undef SOFT_PACK

    // PV: ctx^T[d][q] += Vt[d][key] * P^T[key][q]; l via ones-MFMA (row-sum)
    __builtin_amdgcn_s_setprio(1);
#pragma unroll
    for (int kk = 0; kk < 4; ++kk) {
      bf16x8 vf0 = *(const bf16x8*)(Vb + swzaddr(q, kk * 32 + hi * 16));
      bf16x8 vf1 = *(const bf16x8*)(Vb + swzaddr(32 + q, kk * 32 + hi * 16));
      oacc0 = __builtin_amdgcn_mfma_f32_32x32x16_bf16(vf0, pfrag[kk], oacc0, 0, 0, 0);
      oacc1 = __builtin_amdgcn_mfma_f32_32x32x16_bf16(vf1, pfrag[kk], oacc1, 0, 0, 0);
      oaccL = __builtin_amdgcn_mfma_f32_32x32x16_bf16(ones, pfrag[kk], oaccL, 0, 0, 0);
    }
    __builtin_amdgcn_s_setprio(0);
  }
#undef STAGE

  // epilogue: every oaccL entry = full row-sum l for this lane's q column
  const float inv = 1.0f / oaccL[0];
  const int b = bh >> 4, h = bh & 15;
  const size_t orow = ((size_t)b * SEQ + qt * 256 + w * 32 + q) * 1024 + h * 64;
#pragma unroll
  for (int g = 0; g < 4; ++g) {
    u16x4 o0, o1;
#pragma unroll
    for (int j = 0; j < 4; ++j) {
      o0[j] = f2bf(oacc0[g * 4 + j] * inv);
      o1[j] = f2bf(oacc1[g * 4 + j] * inv);
    }
    *(u16x4*)&CTX[orow + g * 8 + hi * 4] = o0;
    *(u16x4*)&CTX[orow + 32 + g * 8 + hi * 4] = o1;
  }
}

extern "C" void kernel_launch(void* const* d_in, const int* in_sizes, int n_in,
                              void* d_out, int out_size, void* d_ws, size_t ws_size,
                              hipStream_t stream) {
  const float* x  = (const float*)d_in[0];
  const float* e  = (const float*)d_in[1];
  const float* wq = (const float*)d_in[2];
  const float* wk = (const float*)d_in[3];
  const float* wv = (const float*)d_in[4];
  const float* wo = (const float*)d_in[5];
  unsigned short* Wqb = (unsigned short*)d_ws;
  unsigned short* Wkb = Wqb + 1048576;
  unsigned short* Wvb = Wkb + 1048576;
  unsigned short* Wob = Wvb + 1048576;
  unsigned short* Qb  = Wob + 1048576;
  unsigned short* Kb  = Qb + 8388608;
  unsigned short* Vtg = Kb + 8388608;   // V-GEMM writes transposed layout directly
  unsigned short* Cb  = Vtg + 8388608;

  k_cvt_w<<<4096, 256, 0, stream>>>(wq, wk, wv, wo, Wqb, Wkb, Wvb, Wob);

  k_gemm_qkv<<<dim3(8, 64, 3), 256, 0, stream>>>(x, e, Wqb, Wkb, Wvb, Qb, Kb, Vtg);

  k_attn<<<512, 512, 0, stream>>>(Qb, Kb, Vtg, Cb);

  k_gemm_out<<<dim3(8, 64), 256, 0, stream>>>(Cb, Wob, (float*)d_out);
}

// Round 15
// 199.892 us; speedup vs baseline: 1.0098x; 1.0098x over previous
//
#include <hip/hip_runtime.h>
#include <hip/hip_bf16.h>

// CrossMultiHeadAttention: B=4, N=M=2048, D=1024, H=16, hd=64, f32 in/out.
// bf16 pipeline: cvt(weights) -> Q GEMM (f32-A staged) -> merged KV GEMM
// (one E tile feeds both K and V; waves split) -> flash attn -> out GEMM.

typedef __attribute__((ext_vector_type(8))) short bf16x8;
typedef __attribute__((ext_vector_type(4))) float f32x4;
typedef __attribute__((ext_vector_type(16))) float f32x16;
typedef __attribute__((ext_vector_type(4))) unsigned short u16x4;
typedef __attribute__((ext_vector_type(4))) unsigned int u32x4;

#define SEQ 2048
#define H_ 16

static __device__ __forceinline__ unsigned short f2bf(float f) {
  unsigned int u = __float_as_uint(f);
  u += 0x7fffu + ((u >> 16) & 1u);
  return (unsigned short)(u >> 16);
}

static __device__ __forceinline__ void gload16(const void* g, void* l) {
  __builtin_amdgcn_global_load_lds((const __attribute__((address_space(1))) void*)g,
                                   (__attribute__((address_space(3))) void*)l, 16, 0, 0);
}

// Convert the four weight matrices to bf16 (X/E are consumed as f32 by the GEMMs).
__global__ __launch_bounds__(256) void k_cvt_w(const float* __restrict__ wq, const float* __restrict__ wk,
    const float* __restrict__ wv, const float* __restrict__ wo,
    unsigned short* __restrict__ Wqb, unsigned short* __restrict__ Wkb,
    unsigned short* __restrict__ Wvb, unsigned short* __restrict__ Wob) {
  int i = blockIdx.x * 256 + threadIdx.x;   // 4 x 262144 float4 groups
  const float* src; unsigned short* dst; int off;
  if (i < 262144)       { src = wq; dst = Wqb; off = i; }
  else if (i < 524288)  { src = wk; dst = Wkb; off = i - 262144; }
  else if (i < 786432)  { src = wv; dst = Wvb; off = i - 524288; }
  else                  { src = wo; dst = Wob; off = i - 786432; }
  float4 v = reinterpret_cast<const float4*>(src)[off];
  u16x4 o;
  o[0] = f2bf(v.x); o[1] = f2bf(v.y); o[2] = f2bf(v.z); o[3] = f2bf(v.w);
  *reinterpret_cast<u16x4*>(dst + (size_t)off * 4) = o;
}

// XCD co-location decode: all 8 column-blocks of one A row-panel land on the
// same XCD, so the 512KB f32 panel is L2-resident.
static __device__ __forceinline__ void panel_decode(int& col0, int& row0) {
  int lin = blockIdx.x + 8 * blockIdx.y;       // 0..511
  int er = (lin & 7) * 8 + ((lin >> 3) & 7);   // row panel 0..63
  int ec = lin >> 6;                           // col block 0..7
  col0 = ec * 128;
  row0 = er * 128;
}

// R13-proven GEMM core (single-buffer, two barriers/K-step).
// F32A=1: A f32 staged raw (XOR-swizzled source, linear LDS), cvt at read.
template<int F32A, typename EPI>
static __device__ __forceinline__ void gemm_core(char* __restrict__ smem,
                                                 const void* __restrict__ Av,
                                                 const unsigned short* __restrict__ W,
                                                 int col0, int row0, EPI epi) {
  char* AsB = smem;
  unsigned short* Ws = (unsigned short*)(smem + (F32A ? 16384 : 8192));
  const int tid = threadIdx.x, lane = tid & 63, w = tid >> 6;
  const int wr = w >> 1, wc = w & 1;
  f32x4 acc[4][4];
  for (int i = 0; i < 4; ++i)
    for (int j = 0; j < 4; ++j)
      for (int e = 0; e < 4; ++e) acc[i][j][e] = 0.f;

  size_t aoff[F32A ? 4 : 2];
  int aldso[F32A ? 4 : 2];
  if (F32A) {
#pragma unroll
    for (int h = 0; h < 4; ++h) {
      int ch = tid + h * 256;
      int row = ch >> 3, colb = (ch & 7) << 4;
      int ge = (colb ^ ((row & 7) << 4)) >> 2;
      aoff[h] = (size_t)(row0 + row) * 1024 + ge;
      aldso[h] = ch * 16;
    }
  } else {
#pragma unroll
    for (int h = 0; h < 2; ++h) {
      int ch = tid + h * 256;
      int row = ch >> 2, c8 = (ch & 3) * 8;
      aoff[h] = (size_t)(row0 + row) * 1024 + c8;
      aldso[h] = ch * 16;
    }
  }
  size_t woff[2];
  int wldso[2];
#pragma unroll
  for (int h = 0; h < 2; ++h) {
    int ch = tid + h * 256;
    int row = ch >> 2, c8 = (ch & 3) * 8;
    woff[h] = (size_t)(col0 + row) * 1024 + c8;
    wldso[h] = ch * 16;
  }

  const int fr = lane & 15, ko = (lane >> 4) * 8;
  for (int k0 = 0; k0 < 1024; k0 += 32) {
    __syncthreads();
    if (F32A) {
      const float* Af = (const float*)Av;
#pragma unroll
      for (int h = 0; h < 4; ++h)
        gload16(Af + aoff[h] + k0, AsB + aldso[h]);
    } else {
      const unsigned short* Ab = (const unsigned short*)Av;
#pragma unroll
      for (int h = 0; h < 2; ++h)
        gload16(Ab + aoff[h] + k0, AsB + aldso[h]);
    }
#pragma unroll
    for (int h = 0; h < 2; ++h)
      gload16(W + woff[h] + k0, (char*)Ws + wldso[h]);
    __syncthreads();

    bf16x8 af[4], bfr[4];
#pragma unroll
    for (int mi = 0; mi < 4; ++mi) {
      int r = wr * 64 + mi * 16 + fr;
      if (F32A) {
        int swz = (r & 7) << 4;
        int b0 = r * 128 + ko * 4;
        f32x4 x0 = *(const f32x4*)(AsB + ((b0) ^ swz));
        f32x4 x1 = *(const f32x4*)(AsB + ((b0 + 16) ^ swz));
        unsigned pw[4];
        asm("v_cvt_pk_bf16_f32 %0, %1, %2" : "=v"(pw[0]) : "v"(x0[0]), "v"(x0[1]));
        asm("v_cvt_pk_bf16_f32 %0, %1, %2" : "=v"(pw[1]) : "v"(x0[2]), "v"(x0[3]));
        asm("v_cvt_pk_bf16_f32 %0, %1, %2" : "=v"(pw[2]) : "v"(x1[0]), "v"(x1[1]));
        asm("v_cvt_pk_bf16_f32 %0, %1, %2" : "=v"(pw[3]) : "v"(x1[2]), "v"(x1[3]));
        u32x4 fa = { pw[0], pw[1], pw[2], pw[3] };
        af[mi] = __builtin_bit_cast(bf16x8, fa);
      } else {
        af[mi] = *(const bf16x8*)(AsB + (r * 32 + ko) * 2);
      }
    }
#pragma unroll
    for (int ni = 0; ni < 4; ++ni)
      bfr[ni] = *(const bf16x8*)&Ws[(wc * 64 + ni * 16 + fr) * 32 + ko];
#pragma unroll
    for (int mi = 0; mi < 4; ++mi)
#pragma unroll
      for (int ni = 0; ni < 4; ++ni)
        acc[mi][ni] = __builtin_amdgcn_mfma_f32_16x16x32_bf16(af[mi], bfr[ni], acc[mi][ni], 0, 0, 0);
  }
  for (int mi = 0; mi < 4; ++mi)
    for (int ni = 0; ni < 4; ++ni) {
      int r0 = row0 + wr * 64 + mi * 16 + (lane >> 4) * 4;
      int o = col0 + wc * 64 + ni * 16 + (lane & 15);
      epi(r0, o, acc[mi][ni]);
    }
}

// Q projection: Q = X@Wq^T scaled 0.125*log2(e), head layout [B,H,seq,64] bf16.
__global__ __launch_bounds__(256) void k_gemm_q(const float* __restrict__ x,
                                                const unsigned short* __restrict__ Wqb,
                                                unsigned short* __restrict__ Qb) {
  __shared__ __align__(16) char smem[16384 + 8192];
  int col0, row0;
  panel_decode(col0, row0);
  gemm_core<1>(smem, x, Wqb, col0, row0, [&](int r0, int o, f32x4 v) {
    int b = r0 >> 11, n0 = r0 & (SEQ - 1);
    int h = o >> 6, c = o & 63;
    for (int j = 0; j < 4; ++j)
      Qb[(((size_t)(b * H_ + h)) * SEQ + n0 + j) * 64 + c] = f2bf(v[j] * 0.18033688f);
  });
}

// Merged K+V projection: 512 threads, one staged E tile (f32) + Wk + Wv.
// Waves 0-3 compute K (head layout); waves 4-7 compute V (transposed layout).
// Per-thread staging = 2 A + 1 Wk + 1 Wv loads per K-step for TWO outputs.
__global__ __launch_bounds__(512) void k_gemm_kv(const float* __restrict__ e,
                                                 const unsigned short* __restrict__ Wkb,
                                                 const unsigned short* __restrict__ Wvb,
                                                 unsigned short* __restrict__ Kb,
                                                 unsigned short* __restrict__ Vtg) {
  __shared__ __align__(16) char smem[16384 + 8192 + 8192];
  char* AsB = smem;
  unsigned short* Ks = (unsigned short*)(smem + 16384);
  unsigned short* Vs = (unsigned short*)(smem + 24576);
  const int tid = threadIdx.x, lane = tid & 63, w = tid >> 6;
  const int ws = w & 3, isV = w >> 2;
  const int wr = ws >> 1, wc = ws & 1;
  int col0, row0;
  panel_decode(col0, row0);
  f32x4 acc[4][4];
  for (int i = 0; i < 4; ++i)
    for (int j = 0; j < 4; ++j)
      for (int el = 0; el < 4; ++el) acc[i][j][el] = 0.f;

  // A staging: 1024 chunks of 16B; thread handles chunks tid, tid+512.
  size_t aoff[2];
  int aldso[2];
#pragma unroll
  for (int h = 0; h < 2; ++h) {
    int ch = tid + h * 512;
    int row = ch >> 3, colb = (ch & 7) << 4;
    int ge = (colb ^ ((row & 7) << 4)) >> 2;
    aoff[h] = (size_t)(row0 + row) * 1024 + ge;
    aldso[h] = ch * 16;
  }
  // W staging: 512 chunks each; thread handles chunk tid in both Wk and Wv.
  size_t woff;
  int wldso;
  {
    int ch = tid;
    int row = ch >> 2, c8 = (ch & 3) * 8;
    woff = (size_t)(col0 + row) * 1024 + c8;
    wldso = ch * 16;
  }

  const int fr = lane & 15, ko = (lane >> 4) * 8;
  for (int k0 = 0; k0 < 1024; k0 += 32) {
    __syncthreads();
#pragma unroll
    for (int h = 0; h < 2; ++h)
      gload16(e + aoff[h] + k0, AsB + aldso[h]);
    gload16(Wkb + woff + k0, (char*)Ks + wldso);
    gload16(Wvb + woff + k0, (char*)Vs + wldso);
    __syncthreads();

    const unsigned short* Wsel = isV ? Vs : Ks;
    bf16x8 af[4], bfr[4];
#pragma unroll
    for (int mi = 0; mi < 4; ++mi) {
      int r = wr * 64 + mi * 16 + fr;
      int swz = (r & 7) << 4;
      int b0 = r * 128 + ko * 4;
      f32x4 x0 = *(const f32x4*)(AsB + ((b0) ^ swz));
      f32x4 x1 = *(const f32x4*)(AsB + ((b0 + 16) ^ swz));
      unsigned pw[4];
      asm("v_cvt_pk_bf16_f32 %0, %1, %2" : "=v"(pw[0]) : "v"(x0[0]), "v"(x0[1]));
      asm("v_cvt_pk_bf16_f32 %0, %1, %2" : "=v"(pw[1]) : "v"(x0[2]), "v"(x0[3]));
      asm("v_cvt_pk_bf16_f32 %0, %1, %2" : "=v"(pw[2]) : "v"(x1[0]), "v"(x1[1]));
      asm("v_cvt_pk_bf16_f32 %0, %1, %2" : "=v"(pw[3]) : "v"(x1[2]), "v"(x1[3]));
      u32x4 fa = { pw[0], pw[1], pw[2], pw[3] };
      af[mi] = __builtin_bit_cast(bf16x8, fa);
    }
#pragma unroll
    for (int ni = 0; ni < 4; ++ni)
      bfr[ni] = *(const bf16x8*)&Wsel[(wc * 64 + ni * 16 + fr) * 32 + ko];
#pragma unroll
    for (int mi = 0; mi < 4; ++mi)
#pragma unroll
      for (int ni = 0; ni < 4; ++ni)
        acc[mi][ni] = __builtin_amdgcn_mfma_f32_16x16x32_bf16(af[mi], bfr[ni], acc[mi][ni], 0, 0, 0);
  }

  // epilogue
  for (int mi = 0; mi < 4; ++mi)
    for (int ni = 0; ni < 4; ++ni) {
      int r0 = row0 + wr * 64 + mi * 16 + (lane >> 4) * 4;
      int o = col0 + wc * 64 + ni * 16 + (lane & 15);
      int b = r0 >> 11, n0 = r0 & (SEQ - 1);
      int h = o >> 6, c = o & 63;
      if (isV) {
        u16x4 o4;
        for (int j = 0; j < 4; ++j) o4[j] = f2bf(acc[mi][ni][j]);
        *(u16x4*)&Vtg[(((size_t)(b * H_ + h)) * 64 + c) * SEQ + n0] = o4;
      } else {
        for (int j = 0; j < 4; ++j)
          Kb[(((size_t)(b * H_ + h)) * SEQ + n0 + j) * 64 + c] = f2bf(acc[mi][ni][j]);
      }
    }
}

// Final GEMM: out = CTX @ Wo^T, f32 [8192,1024].
__global__ __launch_bounds__(256) void k_gemm_out(const unsigned short* __restrict__ A,
                                                  const unsigned short* __restrict__ W,
                                                  float* __restrict__ out) {
  __shared__ __align__(16) char smem[8192 + 8192];
  int col0, row0;
  panel_decode(col0, row0);
  gemm_core<0>(smem, A, W, col0, row0, [&](int r0, int o, f32x4 v) {
    for (int j = 0; j < 4; ++j)
      out[(size_t)(r0 + j) * 1024 + o] = v[j];
  });
}

static __device__ __forceinline__ int swzaddr(int row, int colb) {
  return row * 128 + (colb ^ ((row & 7) << 4));
}

// Flash attention, no-max softmax (Q pre-scaled to exp2 domain; raw v_exp_f32
// exact for bounded scores). Q,K in [B,H,seq,64]; Vt in [B,H,64,seq];
// CTX [B*N,1024] bf16. 8 waves x 32 q-rows = 256 q-rows/block (512 thr);
// KV tiles of 64, double-buffered. XCD-affine (bh,qt) decode keeps K/V in each
// XCD's L2. l via ones-MFMA (no VALU row-sum/merge).
__global__ __launch_bounds__(512) void k_attn(const unsigned short* __restrict__ Qh,
                                              const unsigned short* __restrict__ Kh,
                                              const unsigned short* __restrict__ Vtg,
                                              unsigned short* __restrict__ CTX) {
  __shared__ __align__(16) char lds[4 * 8192];
  const int tid = threadIdx.x, lane = tid & 63, w = tid >> 6;
  const int hi = lane >> 5, q = lane & 31;
  const int id = blockIdx.x;
  const int bh = (id & 7) * 8 + ((id >> 3) & 7);   // XCD-affine head grouping
  const int qt = id >> 6;                          // 0..7 (256 q-rows per block)
  const size_t kvbase = (size_t)bh * (SEQ * 64);
  const size_t qrow = (size_t)bh * SEQ + qt * 256 + w * 32 + q;
  bf16x8 qf[4];
#pragma unroll
  for (int c = 0; c < 4; ++c)
    qf[c] = *(const bf16x8*)&Qh[qrow * 64 + c * 16 + hi * 8];
  f32x16 oacc0, oacc1, oaccL, fzero;
#pragma unroll
  for (int r = 0; r < 16; ++r) { oacc0[r] = 0.f; oacc1[r] = 0.f; oaccL[r] = 0.f; fzero[r] = 0.f; }
  bf16x8 ones;
#pragma unroll
  for (int r = 0; r < 8; ++r) ones[r] = (short)0x3F80;   // bf16 1.0

  const int sc = tid;
  const int srow = sc >> 3, spb = (sc & 7) << 4;
  const int sge = (spb ^ ((srow & 7) << 4)) >> 1;
  const size_t koff = (size_t)srow * 64 + sge;   // + t*4096
  const size_t voff = (size_t)srow * SEQ + sge;  // + t*64
  const int ldso = sc * 16;

#define STAGE(T, BUFO)                                                        \
  {                                                                           \
    gload16(Kh + kvbase + (size_t)(T) * 4096 + koff, lds + (BUFO) + ldso);    \
    gload16(Vtg + kvbase + (size_t)(T) * 64 + voff, lds + (BUFO) + 8192 + ldso); \
  }

  STAGE(0, 0);

  for (int t = 0; t < 32; ++t) {
    __syncthreads();
    const int bo = (t & 1) * 16384;
    char* Kb = lds + bo;
    char* Vb = lds + bo + 8192;
    if (t + 1 < 32) STAGE(t + 1, ((t + 1) & 1) * 16384);

    f32x16 s0, s1;
    __builtin_amdgcn_s_setprio(1);
    {
      bf16x8 kf0 = *(const bf16x8*)(Kb + swzaddr(q, 0 * 32 + hi * 16));
      bf16x8 kf1 = *(const bf16x8*)(Kb + swzaddr(32 + q, 0 * 32 + hi * 16));
      s0 = __builtin_amdgcn_mfma_f32_32x32x16_bf16(kf0, qf[0], fzero, 0, 0, 0);
      s1 = __builtin_amdgcn_mfma_f32_32x32x16_bf16(kf1, qf[0], fzero, 0, 0, 0);
    }
#pragma unroll
    for (int c = 1; c < 4; ++c) {
      bf16x8 kf0 = *(const bf16x8*)(Kb + swzaddr(q, c * 32 + hi * 16));
      bf16x8 kf1 = *(const bf16x8*)(Kb + swzaddr(32 + q, c * 32 + hi * 16));
      s0 = __builtin_amdgcn_mfma_f32_32x32x16_bf16(kf0, qf[c], s0, 0, 0, 0);
      s1 = __builtin_amdgcn_mfma_f32_32x32x16_bf16(kf1, qf[c], s1, 0, 0, 0);
    }
    __builtin_amdgcn_s_setprio(0);

    bf16x8 pfrag[4];

#define SOFT_PACK(SREG, FA, FB)                                               \
    {                                                                         \
      float pa[16];                                                           \
      _Pragma("unroll")                                                       \
      for (int r = 0; r < 16; ++r) pa[r] = __builtin_amdgcn_exp2f(SREG[r]);   \
      unsigned pw[8];                                                         \
      _Pragma("unroll")                                                       \
      for (int i = 0; i < 8; ++i)                                             \
        asm("v_cvt_pk_bf16_f32 %0, %1, %2" : "=v"(pw[i])                      \
            : "v"(pa[2 * i]), "v"(pa[2 * i + 1]));                            \
      asm("v_permlane32_swap_b32 %0, %1" : "+v"(pw[0]), "+v"(pw[2]));         \
      asm("v_permlane32_swap_b32 %0, %1" : "+v"(pw[1]), "+v"(pw[3]));         \
      asm("v_permlane32_swap_b32 %0, %1" : "+v"(pw[4]), "+v"(pw[6]));         \
      asm("v_permlane32_swap_b32 %0, %1" : "+v"(pw[5]), "+v"(pw[7]));         \
      u32x4 fa = { pw[0], pw[1], pw[2], pw[3] };                              \
      u32x4 fb = { pw[4], pw[5], pw[6], pw[7] };                              \
      FA = __builtin_bit_cast(bf16x8, fa);                                    \
      FB = __builtin_bit_cast(bf16x8, fb);                                    \
    }

    SOFT_PACK(s0, pfrag[0], pfrag[1])
    SOFT_PACK(s1, pfrag[2], pfrag[3])
#undef SOFT_PACK

    __builtin_amdgcn_s_setprio(1);
#pragma unroll
    for (int kk = 0; kk < 4; ++kk) {
      bf16x8 vf0 = *(const bf16x8*)(Vb + swzaddr(q, kk * 32 + hi * 16));
      bf16x8 vf1 = *(const bf16x8*)(Vb + swzaddr(32 + q, kk * 32 + hi * 16));
      oacc0 = __builtin_amdgcn_mfma_f32_32x32x16_bf16(vf0, pfrag[kk], oacc0, 0, 0, 0);
      oacc1 = __builtin_amdgcn_mfma_f32_32x32x16_bf16(vf1, pfrag[kk], oacc1, 0, 0, 0);
      oaccL = __builtin_amdgcn_mfma_f32_32x32x16_bf16(ones, pfrag[kk], oaccL, 0, 0, 0);
    }
    __builtin_amdgcn_s_setprio(0);
  }
#undef STAGE

  const float inv = 1.0f / oaccL[0];
  const int b = bh >> 4, h = bh & 15;
  const size_t orow = ((size_t)b * SEQ + qt * 256 + w * 32 + q) * 1024 + h * 64;
#pragma unroll
  for (int g = 0; g < 4; ++g) {
    u16x4 o0, o1;
#pragma unroll
    for (int j = 0; j < 4; ++j) {
      o0[j] = f2bf(oacc0[g * 4 + j] * inv);
      o1[j] = f2bf(oacc1[g * 4 + j] * inv);
    }
    *(u16x4*)&CTX[orow + g * 8 + hi * 4] = o0;
    *(u16x4*)&CTX[orow + 32 + g * 8 + hi * 4] = o1;
  }
}

extern "C" void kernel_launch(void* const* d_in, const int* in_sizes, int n_in,
                              void* d_out, int out_size, void* d_ws, size_t ws_size,
                              hipStream_t stream) {
  const float* x  = (const float*)d_in[0];
  const float* e  = (const float*)d_in[1];
  const float* wq = (const float*)d_in[2];
  const float* wk = (const float*)d_in[3];
  const float* wv = (const float*)d_in[4];
  const float* wo = (const float*)d_in[5];
  unsigned short* Wqb = (unsigned short*)d_ws;
  unsigned short* Wkb = Wqb + 1048576;
  unsigned short* Wvb = Wkb + 1048576;
  unsigned short* Wob = Wvb + 1048576;
  unsigned short* Qb  = Wob + 1048576;
  unsigned short* Kb  = Qb + 8388608;
  unsigned short* Vtg = Kb + 8388608;
  unsigned short* Cb  = Vtg + 8388608;

  k_cvt_w<<<4096, 256, 0, stream>>>(wq, wk, wv, wo, Wqb, Wkb, Wvb, Wob);

  dim3 gg(8, 64);
  k_gemm_kv<<<gg, 512, 0, stream>>>(e, Wkb, Wvb, Kb, Vtg);
  k_gemm_q<<<gg, 256, 0, stream>>>(x, Wqb, Qb);

  k_attn<<<512, 512, 0, stream>>>(Qb, Kb, Vtg, Cb);

  k_gemm_out<<<gg, 256, 0, stream>>>(Cb, Wob, (float*)d_out);
}

// Round 16
// 190.066 us; speedup vs baseline: 1.0620x; 1.0517x over previous
//
#include <hip/hip_runtime.h>
#include <hip/hip_bf16.h>

// CrossMultiHeadAttention: B=4, N=M=2048, D=1024, H=16, hd=64, f32 in/out.
// bf16 pipeline: cvt(weights) -> fused QKV GEMM (R13 core: f32-A staged,
// XCD-colocated panels, single-buffer) -> flash attn (KVBLK=128 = 2x64-key
// sub-tiles per barrier, 8-wave blocks, XCD-affine, no-max softmax,
// raw v_exp_f32, l via ones-MFMA) -> out GEMM.

typedef __attribute__((ext_vector_type(8))) short bf16x8;
typedef __attribute__((ext_vector_type(4))) float f32x4;
typedef __attribute__((ext_vector_type(16))) float f32x16;
typedef __attribute__((ext_vector_type(4))) unsigned short u16x4;
typedef __attribute__((ext_vector_type(4))) unsigned int u32x4;

#define SEQ 2048
#define H_ 16

static __device__ __forceinline__ unsigned short f2bf(float f) {
  unsigned int u = __float_as_uint(f);
  u += 0x7fffu + ((u >> 16) & 1u);
  return (unsigned short)(u >> 16);
}

static __device__ __forceinline__ void gload16(const void* g, void* l) {
  __builtin_amdgcn_global_load_lds((const __attribute__((address_space(1))) void*)g,
                                   (__attribute__((address_space(3))) void*)l, 16, 0, 0);
}

// Convert the four weight matrices to bf16 (X/E are consumed as f32 by the GEMM).
__global__ __launch_bounds__(256) void k_cvt_w(const float* __restrict__ wq, const float* __restrict__ wk,
    const float* __restrict__ wv, const float* __restrict__ wo,
    unsigned short* __restrict__ Wqb, unsigned short* __restrict__ Wkb,
    unsigned short* __restrict__ Wvb, unsigned short* __restrict__ Wob) {
  int i = blockIdx.x * 256 + threadIdx.x;   // 4 x 262144 float4 groups
  const float* src; unsigned short* dst; int off;
  if (i < 262144)       { src = wq; dst = Wqb; off = i; }
  else if (i < 524288)  { src = wk; dst = Wkb; off = i - 262144; }
  else if (i < 786432)  { src = wv; dst = Wvb; off = i - 524288; }
  else                  { src = wo; dst = Wob; off = i - 786432; }
  float4 v = reinterpret_cast<const float4*>(src)[off];
  u16x4 o;
  o[0] = f2bf(v.x); o[1] = f2bf(v.y); o[2] = f2bf(v.z); o[3] = f2bf(v.w);
  *reinterpret_cast<u16x4*>(dst + (size_t)off * 4) = o;
}

// R13-proven GEMM core (single-buffer, two barriers/K-step).
// F32A=1: A f32 staged raw (XOR-swizzled source, linear LDS), cvt at read.
template<int F32A, typename EPI>
static __device__ __forceinline__ void gemm_core(char* __restrict__ smem,
                                                 const void* __restrict__ Av,
                                                 const unsigned short* __restrict__ W,
                                                 int col0, int row0, EPI epi) {
  char* AsB = smem;
  unsigned short* Ws = (unsigned short*)(smem + (F32A ? 16384 : 8192));
  const int tid = threadIdx.x, lane = tid & 63, w = tid >> 6;
  const int wr = w >> 1, wc = w & 1;
  f32x4 acc[4][4];
  for (int i = 0; i < 4; ++i)
    for (int j = 0; j < 4; ++j)
      for (int e = 0; e < 4; ++e) acc[i][j][e] = 0.f;

  size_t aoff[F32A ? 4 : 2];
  int aldso[F32A ? 4 : 2];
  if (F32A) {
#pragma unroll
    for (int h = 0; h < 4; ++h) {
      int ch = tid + h * 256;
      int row = ch >> 3, colb = (ch & 7) << 4;
      int ge = (colb ^ ((row & 7) << 4)) >> 2;
      aoff[h] = (size_t)(row0 + row) * 1024 + ge;
      aldso[h] = ch * 16;
    }
  } else {
#pragma unroll
    for (int h = 0; h < 2; ++h) {
      int ch = tid + h * 256;
      int row = ch >> 2, c8 = (ch & 3) * 8;
      aoff[h] = (size_t)(row0 + row) * 1024 + c8;
      aldso[h] = ch * 16;
    }
  }
  size_t woff[2];
  int wldso[2];
#pragma unroll
  for (int h = 0; h < 2; ++h) {
    int ch = tid + h * 256;
    int row = ch >> 2, c8 = (ch & 3) * 8;
    woff[h] = (size_t)(col0 + row) * 1024 + c8;
    wldso[h] = ch * 16;
  }

  const int fr = lane & 15, ko = (lane >> 4) * 8;
  for (int k0 = 0; k0 < 1024; k0 += 32) {
    __syncthreads();
    if (F32A) {
      const float* Af = (const float*)Av;
#pragma unroll
      for (int h = 0; h < 4; ++h)
        gload16(Af + aoff[h] + k0, AsB + aldso[h]);
    } else {
      const unsigned short* Ab = (const unsigned short*)Av;
#pragma unroll
      for (int h = 0; h < 2; ++h)
        gload16(Ab + aoff[h] + k0, AsB + aldso[h]);
    }
#pragma unroll
    for (int h = 0; h < 2; ++h)
      gload16(W + woff[h] + k0, (char*)Ws + wldso[h]);
    __syncthreads();

    bf16x8 af[4], bfr[4];
#pragma unroll
    for (int mi = 0; mi < 4; ++mi) {
      int r = wr * 64 + mi * 16 + fr;
      if (F32A) {
        int swz = (r & 7) << 4;
        int b0 = r * 128 + ko * 4;
        f32x4 x0 = *(const f32x4*)(AsB + ((b0) ^ swz));
        f32x4 x1 = *(const f32x4*)(AsB + ((b0 + 16) ^ swz));
        unsigned pw[4];
        asm("v_cvt_pk_bf16_f32 %0, %1, %2" : "=v"(pw[0]) : "v"(x0[0]), "v"(x0[1]));
        asm("v_cvt_pk_bf16_f32 %0, %1, %2" : "=v"(pw[1]) : "v"(x0[2]), "v"(x0[3]));
        asm("v_cvt_pk_bf16_f32 %0, %1, %2" : "=v"(pw[2]) : "v"(x1[0]), "v"(x1[1]));
        asm("v_cvt_pk_bf16_f32 %0, %1, %2" : "=v"(pw[3]) : "v"(x1[2]), "v"(x1[3]));
        u32x4 fa = { pw[0], pw[1], pw[2], pw[3] };
        af[mi] = __builtin_bit_cast(bf16x8, fa);
      } else {
        af[mi] = *(const bf16x8*)(AsB + (r * 32 + ko) * 2);
      }
    }
#pragma unroll
    for (int ni = 0; ni < 4; ++ni)
      bfr[ni] = *(const bf16x8*)&Ws[(wc * 64 + ni * 16 + fr) * 32 + ko];
#pragma unroll
    for (int mi = 0; mi < 4; ++mi)
#pragma unroll
      for (int ni = 0; ni < 4; ++ni)
        acc[mi][ni] = __builtin_amdgcn_mfma_f32_16x16x32_bf16(af[mi], bfr[ni], acc[mi][ni], 0, 0, 0);
  }
  for (int mi = 0; mi < 4; ++mi)
    for (int ni = 0; ni < 4; ++ni) {
      int r0 = row0 + wr * 64 + mi * 16 + (lane >> 4) * 4;
      int o = col0 + wc * 64 + ni * 16 + (lane & 15);
      epi(r0, o, acc[mi][ni]);
    }
}

// XCD co-location decode: all 8 column-blocks of one A row-panel land on the
// same XCD, so the 512KB f32 panel is L2-resident.
static __device__ __forceinline__ void panel_decode(int& col0, int& row0) {
  int lin = blockIdx.x + 8 * blockIdx.y;       // 0..511
  int er = (lin & 7) * 8 + ((lin >> 3) & 7);   // row panel 0..63
  int ec = lin >> 6;                           // col block 0..7
  col0 = ec * 128;
  row0 = er * 128;
}

// Fused Q/K/V projection GEMM; blockIdx.z selects path (block-uniform).
__global__ __launch_bounds__(256) void k_gemm_qkv(const float* __restrict__ x,
                                                  const float* __restrict__ e,
                                                  const unsigned short* __restrict__ Wqb,
                                                  const unsigned short* __restrict__ Wkb,
                                                  const unsigned short* __restrict__ Wvb,
                                                  unsigned short* __restrict__ Qb,
                                                  unsigned short* __restrict__ Kb,
                                                  unsigned short* __restrict__ Vtg) {
  __shared__ __align__(16) char smem[16384 + 8192];
  const int z = blockIdx.z;
  int col0, row0;
  panel_decode(col0, row0);
  const void* A = (z == 0) ? (const void*)x : (const void*)e;
  const unsigned short* W = (z == 0) ? Wqb : (z == 1) ? Wkb : Wvb;
  if (z == 2) {
    gemm_core<1>(smem, A, W, col0, row0, [&](int r0, int o, f32x4 v) {
      int b = r0 >> 11, n0 = r0 & (SEQ - 1);
      int h = o >> 6, c = o & 63;
      u16x4 o4;
      for (int j = 0; j < 4; ++j) o4[j] = f2bf(v[j]);
      *(u16x4*)&Vtg[(((size_t)(b * H_ + h)) * 64 + c) * SEQ + n0] = o4;
    });
  } else {
    unsigned short* out = (z == 0) ? Qb : Kb;
    const float sc = (z == 0) ? 0.18033688f : 1.0f;   // 0.125 * log2(e)
    gemm_core<1>(smem, A, W, col0, row0, [&](int r0, int o, f32x4 v) {
      int b = r0 >> 11, n0 = r0 & (SEQ - 1);
      int h = o >> 6, c = o & 63;
      for (int j = 0; j < 4; ++j)
        out[(((size_t)(b * H_ + h)) * SEQ + n0 + j) * 64 + c] = f2bf(v[j] * sc);
    });
  }
}

// Final GEMM: out = CTX @ Wo^T, f32 [8192,1024].
__global__ __launch_bounds__(256) void k_gemm_out(const unsigned short* __restrict__ A,
                                                  const unsigned short* __restrict__ W,
                                                  float* __restrict__ out) {
  __shared__ __align__(16) char smem[8192 + 8192];
  int col0, row0;
  panel_decode(col0, row0);
  gemm_core<0>(smem, A, W, col0, row0, [&](int r0, int o, f32x4 v) {
    for (int j = 0; j < 4; ++j)
      out[(size_t)(r0 + j) * 1024 + o] = v[j];
  });
}

static __device__ __forceinline__ int swzaddr(int row, int colb) {
  return row * 128 + (colb ^ ((row & 7) << 4));
}

// Flash attention, no-max softmax (Q pre-scaled to exp2 domain; raw v_exp_f32
// exact for bounded scores). Q,K in [B,H,seq,64]; Vt in [B,H,64,seq];
// CTX [B*N,1024] bf16. 8 waves x 32 q-rows = 256 q-rows/block (512 thr).
// KVBLK=128 per barrier: each iteration stages TWO 64-key sub-tiles (the
// R10-proven 8KB K + 8KB V unit, byte-identical layout/swizzle) and runs the
// proven 64-key body twice. Halves the __syncthreads/vmcnt-drain count; the
// prefetch gets a 2x compute phase to land under. LDS 2 x 32KB = 64KB ->
// still 2 blocks/CU. XCD-affine (bh,qt) decode keeps K/V in each XCD's L2.
// l via ones-MFMA (no VALU row-sum/merge).
__global__ __launch_bounds__(512) void k_attn(const unsigned short* __restrict__ Qh,
                                              const unsigned short* __restrict__ Kh,
                                              const unsigned short* __restrict__ Vtg,
                                              unsigned short* __restrict__ CTX) {
  __shared__ __align__(16) char lds[2 * 32768];
  const int tid = threadIdx.x, lane = tid & 63, w = tid >> 6;
  const int hi = lane >> 5, q = lane & 31;
  const int id = blockIdx.x;
  const int bh = (id & 7) * 8 + ((id >> 3) & 7);   // XCD-affine head grouping
  const int qt = id >> 6;                          // 0..7 (256 q-rows per block)
  const size_t kvbase = (size_t)bh * (SEQ * 64);
  const size_t qrow = (size_t)bh * SEQ + qt * 256 + w * 32 + q;
  bf16x8 qf[4];
#pragma unroll
  for (int c = 0; c < 4; ++c)
    qf[c] = *(const bf16x8*)&Qh[qrow * 64 + c * 16 + hi * 8];
  f32x16 oacc0, oacc1, oaccL, fzero;
#pragma unroll
  for (int r = 0; r < 16; ++r) { oacc0[r] = 0.f; oacc1[r] = 0.f; oaccL[r] = 0.f; fzero[r] = 0.f; }
  bf16x8 ones;
#pragma unroll
  for (int r = 0; r < 8; ++r) ones[r] = (short)0x3F80;   // bf16 1.0

  // staging unit (64 keys): 512 16B chunks K + 512 chunks V; each of 512
  // threads stages 1 K-chunk + 1 V-chunk. LDS linear; global source
  // pre-swizzled so reads use colb ^ ((row&7)<<4).
  const int sc = tid;
  const int srow = sc >> 3, spb = (sc & 7) << 4;
  const int sge = (spb ^ ((srow & 7) << 4)) >> 1;
  const size_t koff = (size_t)srow * 64 + sge;   // + T*4096 (T in 64-key units)
  const size_t voff = (size_t)srow * SEQ + sge;  // + T*64
  const int ldso = sc * 16;

  // 64-key stage unit: [K 8KB][V 8KB] at BUFO
#define STAGE64(T, BUFO)                                                      \
  {                                                                           \
    gload16(Kh + kvbase + (size_t)(T) * 4096 + koff, lds + (BUFO) + ldso);    \
    gload16(Vtg + kvbase + (size_t)(T) * 64 + voff, lds + (BUFO) + 8192 + ldso); \
  }
  // 128-key tile: two 64-key units at BUFO, BUFO+16384
#define STAGE128(TT, BUFO)                                                    \
  {                                                                           \
    STAGE64(2 * (TT), BUFO);                                                  \
    STAGE64(2 * (TT) + 1, (BUFO) + 16384);                                    \
  }

  STAGE128(0, 0);

  for (int t = 0; t < 16; ++t) {
    __syncthreads();  // drains vmcnt -> buf[t&1] ready, buf[t&1^1] free
    const int bo = (t & 1) * 32768;
    if (t + 1 < 16) STAGE128(t + 1, ((t + 1) & 1) * 32768);

#pragma unroll
    for (int s = 0; s < 2; ++s) {
      char* Kb = lds + bo + s * 16384;
      char* Vb = Kb + 8192;

      // QK^T (swapped): s[half] = S^T[key][q], already in exp2 domain
      f32x16 s0, s1;
      __builtin_amdgcn_s_setprio(1);
      {
        bf16x8 kf0 = *(const bf16x8*)(Kb + swzaddr(q, 0 * 32 + hi * 16));
        bf16x8 kf1 = *(const bf16x8*)(Kb + swzaddr(32 + q, 0 * 32 + hi * 16));
        s0 = __builtin_amdgcn_mfma_f32_32x32x16_bf16(kf0, qf[0], fzero, 0, 0, 0);
        s1 = __builtin_amdgcn_mfma_f32_32x32x16_bf16(kf1, qf[0], fzero, 0, 0, 0);
      }
#pragma unroll
      for (int c = 1; c < 4; ++c) {
        bf16x8 kf0 = *(const bf16x8*)(Kb + swzaddr(q, c * 32 + hi * 16));
        bf16x8 kf1 = *(const bf16x8*)(Kb + swzaddr(32 + q, c * 32 + hi * 16));
        s0 = __builtin_amdgcn_mfma_f32_32x32x16_bf16(kf0, qf[c], s0, 0, 0, 0);
        s1 = __builtin_amdgcn_mfma_f32_32x32x16_bf16(kf1, qf[c], s1, 0, 0, 0);
      }
      __builtin_amdgcn_s_setprio(0);

      bf16x8 pfrag[4];

#define SOFT_PACK(SREG, FA, FB)                                               \
      {                                                                       \
        float pa[16];                                                         \
        _Pragma("unroll")                                                     \
        for (int r = 0; r < 16; ++r) pa[r] = __builtin_amdgcn_exp2f(SREG[r]); \
        unsigned pw[8];                                                       \
        _Pragma("unroll")                                                     \
        for (int i = 0; i < 8; ++i)                                           \
          asm("v_cvt_pk_bf16_f32 %0, %1, %2" : "=v"(pw[i])                    \
              : "v"(pa[2 * i]), "v"(pa[2 * i + 1]));                          \
        asm("v_permlane32_swap_b32 %0, %1" : "+v"(pw[0]), "+v"(pw[2]));       \
        asm("v_permlane32_swap_b32 %0, %1" : "+v"(pw[1]), "+v"(pw[3]));       \
        asm("v_permlane32_swap_b32 %0, %1" : "+v"(pw[4]), "+v"(pw[6]));       \
        asm("v_permlane32_swap_b32 %0, %1" : "+v"(pw[5]), "+v"(pw[7]));       \
        u32x4 fa = { pw[0], pw[1], pw[2], pw[3] };                            \
        u32x4 fb = { pw[4], pw[5], pw[6], pw[7] };                            \
        FA = __builtin_bit_cast(bf16x8, fa);                                  \
        FB = __builtin_bit_cast(bf16x8, fb);                                  \
      }

      SOFT_PACK(s0, pfrag[0], pfrag[1])
      SOFT_PACK(s1, pfrag[2], pfrag[3])
#undef SOFT_PACK

      // PV: ctx^T[d][q] += Vt[d][key] * P^T[key][q]; l via ones-MFMA
      __builtin_amdgcn_s_setprio(1);
#pragma unroll
      for (int kk = 0; kk < 4; ++kk) {
        bf16x8 vf0 = *(const bf16x8*)(Vb + swzaddr(q, kk * 32 + hi * 16));
        bf16x8 vf1 = *(const bf16x8*)(Vb + swzaddr(32 + q, kk * 32 + hi * 16));
        oacc0 = __builtin_amdgcn_mfma_f32_32x32x16_bf16(vf0, pfrag[kk], oacc0, 0, 0, 0);
        oacc1 = __builtin_amdgcn_mfma_f32_32x32x16_bf16(vf1, pfrag[kk], oacc1, 0, 0, 0);
        oaccL = __builtin_amdgcn_mfma_f32_32x32x16_bf16(ones, pfrag[kk], oaccL, 0, 0, 0);
      }
      __builtin_amdgcn_s_setprio(0);
    }
  }
#undef STAGE64
#undef STAGE128

  // epilogue: every oaccL entry = full row-sum l for this lane's q column
  const float inv = 1.0f / oaccL[0];
  const int b = bh >> 4, h = bh & 15;
  const size_t orow = ((size_t)b * SEQ + qt * 256 + w * 32 + q) * 1024 + h * 64;
#pragma unroll
  for (int g = 0; g < 4; ++g) {
    u16x4 o0, o1;
#pragma unroll
    for (int j = 0; j < 4; ++j) {
      o0[j] = f2bf(oacc0[g * 4 + j] * inv);
      o1[j] = f2bf(oacc1[g * 4 + j] * inv);
    }
    *(u16x4*)&CTX[orow + g * 8 + hi * 4] = o0;
    *(u16x4*)&CTX[orow + 32 + g * 8 + hi * 4] = o1;
  }
}

extern "C" void kernel_launch(void* const* d_in, const int* in_sizes, int n_in,
                              void* d_out, int out_size, void* d_ws, size_t ws_size,
                              hipStream_t stream) {
  const float* x  = (const float*)d_in[0];
  const float* e  = (const float*)d_in[1];
  const float* wq = (const float*)d_in[2];
  const float* wk = (const float*)d_in[3];
  const float* wv = (const float*)d_in[4];
  const float* wo = (const float*)d_in[5];
  unsigned short* Wqb = (unsigned short*)d_ws;
  unsigned short* Wkb = Wqb + 1048576;
  unsigned short* Wvb = Wkb + 1048576;
  unsigned short* Wob = Wvb + 1048576;
  unsigned short* Qb  = Wob + 1048576;
  unsigned short* Kb  = Qb + 8388608;
  unsigned short* Vtg = Kb + 8388608;   // V-GEMM writes transposed layout directly
  unsigned short* Cb  = Vtg + 8388608;

  k_cvt_w<<<4096, 256, 0, stream>>>(wq, wk, wv, wo, Wqb, Wkb, Wvb, Wob);

  k_gemm_qkv<<<dim3(8, 64, 3), 256, 0, stream>>>(x, e, Wqb, Wkb, Wvb, Qb, Kb, Vtg);

  k_attn<<<512, 512, 0, stream>>>(Qb, Kb, Vtg, Cb);

  k_gemm_out<<<dim3(8, 64), 256, 0, stream>>>(Cb, Wob, (float*)d_out);
}